// Round 6
// baseline (788.307 us; speedup 1.0000x reference)
//
#include <hip/hip_runtime.h>
#include <math.h>

#define NCLS 19      // known classes (void = 19 dropped)
#define NF   256     // feature length
#define HW   16384   // 128*128 pixels per image
#define NB   16      // batch
#define PX   (NB*HW) // 262144 total pixels

// ---- K0: zero scratch (nrm2 accumulator + gproto) ----
__global__ __launch_bounds__(256) void zero_ws(float* __restrict__ nrm2,
                                               float* __restrict__ gproto) {
    int i = blockIdx.x * 256 + threadIdx.x;
    if (i < PX) nrm2[i] = 0.f;
    if (i < NCLS * NF) gproto[i] = 0.f;
}

// ---- K1: per-pixel sum-of-squares ----
// R6 change: 1024-thread blocks -> 32 waves/CU (was 8). R2/R4/R5 all showed a
// flat ~0.7 GB/s per wave regardless of MLP/pattern; the 6.3TB/s copy bench
// differs only in waves/CU (32). Structure otherwise identical to R5.
// grid 512: b = g>>5, f0 = (g&31)*8; block sweeps 8 f-slices (contiguous 512KB).
__global__ __launch_bounds__(1024) void sumsq_kernel(const float* __restrict__ feat,
                                                     float* __restrict__ nrm2) {
    const int g  = blockIdx.x;
    const int b  = g >> 5;
    const int f0 = (g & 31) << 3;
    const int t  = threadIdx.x;

    const float* base = feat + (size_t)(b * NF + f0) * HW + t * 4;
    float* np = nrm2 + b * HW + t * 4;

    for (int k = 0; k < 4; ++k) {            // pixel chunk: p = k*4096 + t*4 + j
        float4 v[8];
        #pragma unroll
        for (int s = 0; s < 8; ++s)
            v[s] = *(const float4*)(base + (size_t)s * HW + k * 4096);
        float a0 = 0.f, a1 = 0.f, a2 = 0.f, a3 = 0.f;
        #pragma unroll
        for (int s = 0; s < 8; ++s) {
            a0 += v[s].x * v[s].x;
            a1 += v[s].y * v[s].y;
            a2 += v[s].z * v[s].z;
            a3 += v[s].w * v[s].w;
        }
        atomicAdd(&np[k * 4096 + 0], a0);
        atomicAdd(&np[k * 4096 + 1], a1);
        atomicAdd(&np[k * 4096 + 2], a2);
        atomicAdd(&np[k * 4096 + 3], a3);
    }
}

// ---- K2: nrm2 -> 1/max(sqrt(nrm2), eps), in place ----
__global__ __launch_bounds__(256) void rinv_kernel(float* __restrict__ nrm2) {
    int i = (blockIdx.x * 256 + threadIdx.x) * 4;
    float4 s = *(float4*)(nrm2 + i);
    float4 r;
    r.x = 1.f / fmaxf(sqrtf(s.x), 1e-12f);
    r.y = 1.f / fmaxf(sqrtf(s.y), 1e-12f);
    r.z = 1.f / fmaxf(sqrtf(s.z), 1e-12f);
    r.w = 1.f / fmaxf(sqrtf(s.w), 1e-12f);
    *(float4*)(nrm2 + i) = r;
}

// ---- K3: scaled scatter into class prototypes ----
// grid 512 x 1024 thr: same (b, f0) tiling as K1. LDS tile 19x9 (9 coprime 32).
__global__ __launch_bounds__(1024) void scatter_kernel(const float* __restrict__ feat,
                                                       const int* __restrict__ labels,
                                                       const float* __restrict__ rinv,
                                                       float* __restrict__ gproto) {
    __shared__ float lp[NCLS * 9];
    const int t = threadIdx.x;
    if (t < NCLS * 9) lp[t] = 0.f;
    __syncthreads();

    const int g  = blockIdx.x;
    const int b  = g >> 5;
    const int f0 = (g & 31) << 3;

    const float* base = feat + (size_t)(b * NF + f0) * HW + t * 4;
    const int*   lb   = labels + b * HW + t * 4;
    const float* rv   = rinv   + b * HW + t * 4;

    for (int k = 0; k < 4; ++k) {
        const int4   l4 = *(const int4*)(lb + k * 4096);
        const float4 r4 = *(const float4*)(rv + k * 4096);
        float4 v[8];
        #pragma unroll
        for (int s = 0; s < 8; ++s)
            v[s] = *(const float4*)(base + (size_t)s * HW + k * 4096);
        #pragma unroll
        for (int s = 0; s < 8; ++s) {
            if (l4.x < NCLS) atomicAdd(&lp[l4.x * 9 + s], v[s].x * r4.x);
            if (l4.y < NCLS) atomicAdd(&lp[l4.y * 9 + s], v[s].y * r4.y);
            if (l4.z < NCLS) atomicAdd(&lp[l4.z * 9 + s], v[s].z * r4.z);
            if (l4.w < NCLS) atomicAdd(&lp[l4.w * 9 + s], v[s].w * r4.w);
        }
    }
    __syncthreads();

    if (t < NCLS * 8) {
        const int c = t >> 3, fr = t & 7;
        const float val = lp[c * 9 + fr];
        if (val != 0.f) atomicAdd(&gproto[c * NF + f0 + fr], val);
    }
}

// ---- K4: normalize prototype columns, write transposed out[f*19+c] ----
__global__ __launch_bounds__(256) void normalize_protos(const float* __restrict__ gproto,
                                                        float* __restrict__ out) {
    __shared__ float ws[4];
    const int c = blockIdx.x;
    const int f = threadIdx.x;
    const float v = gproto[c * NF + f];

    float s = v * v;
    #pragma unroll
    for (int off = 32; off > 0; off >>= 1) s += __shfl_down(s, off, 64);
    if ((f & 63) == 0) ws[f >> 6] = s;
    __syncthreads();
    const float tot = ws[0] + ws[1] + ws[2] + ws[3];
    const float rn = 1.f / fmaxf(sqrtf(tot), 1e-12f);
    out[f * NCLS + c] = v * rn;
}

extern "C" void kernel_launch(void* const* d_in, const int* in_sizes, int n_in,
                              void* d_out, int out_size, void* d_ws, size_t ws_size,
                              hipStream_t stream) {
    const float* feat   = (const float*)d_in[0];
    const int*   labels = (const int*)d_in[1];
    float* out    = (float*)d_out;
    float* gproto = (float*)d_ws;              // 4864 floats (slot of 8192)
    float* nrm2   = (float*)d_ws + 8192;       // 262144 floats (1 MB)

    zero_ws<<<PX / 256, 256, 0, stream>>>(nrm2, gproto);      // 1024 blocks
    sumsq_kernel<<<512, 1024, 0, stream>>>(feat, nrm2);
    rinv_kernel<<<PX / 1024, 256, 0, stream>>>(nrm2);         // 256 blocks
    scatter_kernel<<<512, 1024, 0, stream>>>(feat, labels, nrm2, gproto);
    normalize_protos<<<NCLS, 256, 0, stream>>>(gproto, out);
}